// Round 5
// baseline (216.466 us; speedup 1.0000x reference)
//
#include <hip/hip_runtime.h>

#define B_   4
#define H_   128
#define W_   128
#define HW_  (H_*W_)     // 16384
#define CIN_ 1152
#define CP   72          // padded channel stride in LDS (144 B, 16B-aligned)

typedef __attribute__((ext_vector_type(8))) short short8;
typedef __attribute__((ext_vector_type(4))) float floatx4;
typedef unsigned short u16;
typedef unsigned int   u32;

__device__ __forceinline__ float bf2f(u16 u){ union{u32 i; float f;} v; v.i=((u32)u)<<16; return v.f; }
__device__ __forceinline__ u16 f2bf(float f){ union{float fl; u32 i;} v; v.fl=f; u32 lsb=(v.i>>16)&1u; v.i += 0x7fffu + lsb; return (u16)(v.i>>16); }

// ---------------------------------------------------------------------------
// K1: re-layout w1 (fp32 [64][1152], col = half*576 + c*9 + ij) into bf16
//     Wt{A,B}[o][ij*64 + c]
__global__ void k_prep_w(const float* __restrict__ w1,
                         u16* __restrict__ WtA, u16* __restrict__ WtB){
    int o = blockIdx.x, sel = blockIdx.y, k = threadIdx.x;   // k in [0,576)
    int c = k & 63, ij = k >> 6;
    float v = w1[(long)o*CIN_ + sel*576 + c*9 + ij];
    u16* dst = sel ? WtB : WtA;
    dst[o*576 + ij*64 + c] = f2bf(v);
}

// ---------------------------------------------------------------------------
// K2 (tier A only): nbh fp32 NCHW -> bf16 NHWC (for k_attn's coalesced gather)
__global__ void k_t_nbh(const float* __restrict__ nbh, u16* __restrict__ nbhT){
    __shared__ u16 tile[64*66];
    int px0 = blockIdx.x * 64;
    int b   = blockIdx.y;
    int t   = threadIdx.x;
    #pragma unroll
    for (int it = 0; it < 16; ++it){
        int c  = it*4 + (t>>6);
        int px = t & 63;                       // coalesced along px
        tile[c*66+px] = f2bf(nbh[(long)(b*64 + c)*HW_ + px0 + px]);
    }
    __syncthreads();
    #pragma unroll
    for (int it = 0; it < 16; ++it){
        int c  = t & 63;                       // coalesced along c
        int px = it*4 + (t>>6);
        nbhT[(size_t)(b*HW_ + px0 + px)*64 + c] = tile[c*66+px];
    }
}

// ---------------------------------------------------------------------------
// K3: 3x3 conv cin=64 -> cout=64, zero pad, MFMA 16x16x32 bf16 (this exact
//     MFMA core was exonerated by the r4 VALU bisection: identical output).
__global__ __launch_bounds__(256) void k_conv(
        const float* __restrict__ nbh, const float* __restrict__ cen,
        const u16* __restrict__ WtA, const u16* __restrict__ WtB,
        u16* __restrict__ convA, u16* __restrict__ convB){
    __shared__ __align__(16) u16 patch[3*66*CP];   // rows y-1..y+1, cols x0-1..x0+64
    __shared__ __align__(16) u16 wtile[64*CP];     // [o][c] for current shift
    int x0  = blockIdx.x * 64;
    int y   = blockIdx.y;
    int b   = blockIdx.z >> 1;
    int sel = blockIdx.z & 1;
    const float* src = sel ? cen : nbh;
    const u16* wt    = sel ? WtB : WtA;
    u16* dst         = sel ? convB : convA;
    int tid = threadIdx.x;

    // stage patch from fp32 NCHW (zero OOB = unfold's zero padding)
    #pragma unroll
    for (int i = 0; i < 3; ++i){
        int ry = y + i - 1;
        for (int q = tid; q < 64*66; q += 256){
            int c = q / 66, tcol = q - c*66;
            int gx = x0 - 1 + tcol;
            float v = 0.f;
            if (ry >= 0 && ry < H_ && gx >= 0 && gx < W_)
                v = src[((long)(b*64 + c))*HW_ + ry*W_ + gx];
            patch[(i*66 + tcol)*CP + c] = f2bf(v);
        }
    }

    int lane = tid & 63;
    int m    = lane & 15;
    int qd   = lane >> 4;
    int wpx0 = (tid >> 6) * 16;

    floatx4 acc[4] = { {0,0,0,0},{0,0,0,0},{0,0,0,0},{0,0,0,0} };

    #pragma unroll
    for (int ij = 0; ij < 9; ++ij){
        const int i = ij / 3, j = ij % 3;
        __syncthreads();                       // covers patch staging at ij==0
        for (int q = tid; q < 64*8; q += 256){ // stage 64x64 weight tile
            int o = q >> 3, c8 = q & 7;
            *reinterpret_cast<uint4*>(&wtile[o*CP + c8*8]) =
                *reinterpret_cast<const uint4*>(&wt[o*576 + ij*64 + c8*8]);
        }
        __syncthreads();
        #pragma unroll
        for (int s = 0; s < 2; ++s){
            int c0 = s*32 + qd*8;
            short8 a = *reinterpret_cast<const short8*>(&patch[(i*66 + wpx0 + m + j)*CP + c0]);
            #pragma unroll
            for (int nt = 0; nt < 4; ++nt){
                short8 bv = *reinterpret_cast<const short8*>(&wtile[(nt*16 + m)*CP + c0]);
                acc[nt] = __builtin_amdgcn_mfma_f32_16x16x32_bf16(a, bv, acc[nt], 0, 0, 0);
            }
        }
    }

    // C/D layout: col(o-local) = lane&15, row(px-local) = quad*4 + reg
    size_t base = ((size_t)(b*HW_ + y*W_ + x0))*64;
    #pragma unroll
    for (int nt = 0; nt < 4; ++nt)
        #pragma unroll
        for (int r = 0; r < 4; ++r){
            int px = wpx0 + qd*4 + r;
            int o  = nt*16 + m;
            dst[base + (size_t)px*64 + o] = f2bf(acc[nt][r]);
        }
}

// ---------------------------------------------------------------------------
// K4: one wave per pixel. h1 = bilin(convA) + convB + b1 -> leaky -> h2 ->
//     softmax -> 16-tap combined-weight gather.
__global__ __launch_bounds__(256) void k_attn(
        const float* __restrict__ nbhRaw, const u16* __restrict__ nbhT,
        const u16* __restrict__ convA, const u16* __restrict__ convB,
        const float* __restrict__ mv,
        const float* __restrict__ b1, const float* __restrict__ w2,
        const float* __restrict__ b2,
        u16* __restrict__ outT, float* __restrict__ outN, int tierA){
    int tid  = threadIdx.x;
    int lane = tid & 63;
    int P    = blockIdx.x*4 + (tid >> 6);
    int b    = P >> 14;
    int rem  = P & 16383;
    int y    = rem >> 7;
    int x    = rem & 127;

    // u = mv0/W*2*32 = 0.5*mv0 ; align_corners=True
    float u  = mv[(long)(b*2  )*HW_ + y*W_ + x] * 0.5f;
    float v  = mv[(long)(b*2+1)*HW_ + y*W_ + x] * 0.5f;
    float gx = fminf(fmaxf(-1.0f + x*(2.0f/127.0f) + u, -1.f), 1.f);
    float gy = fminf(fmaxf(-1.0f + y*(2.0f/127.0f) + v, -1.f), 1.f);
    float sx = (gx + 1.f) * 63.5f;
    float sy = (gy + 1.f) * 63.5f;
    float x0f = floorf(sx), y0f = floorf(sy);
    float wx = sx - x0f,    wy = sy - y0f;
    int x0i = min(max((int)x0f, 0), W_-1);
    int y0i = min(max((int)y0f, 0), H_-1);
    int x1i = min(x0i+1, W_-1);
    int y1i = min(y0i+1, H_-1);
    float wx0 = 1.f - wx, wy0 = 1.f - wy;

    size_t pb = (size_t)b*HW_*64;
    int o = lane;
    float v00 = bf2f(convA[pb + (size_t)(y0i*W_+x0i)*64 + o]);
    float v01 = bf2f(convA[pb + (size_t)(y0i*W_+x1i)*64 + o]);
    float v10 = bf2f(convA[pb + (size_t)(y1i*W_+x0i)*64 + o]);
    float v11 = bf2f(convA[pb + (size_t)(y1i*W_+x1i)*64 + o]);
    float h1 = wy0*wx0*v00 + wy0*wx*v01 + wy*wx0*v10 + wy*wx*v11
             + bf2f(convB[pb + (size_t)(y*W_+x)*64 + o]) + b1[o];
    h1 = h1 >= 0.f ? h1 : 0.1f*h1;   // LeakyReLU(0.1)

    float e[9];
    #pragma unroll
    for (int k = 0; k < 9; ++k){
        float p = h1 * w2[k*64 + o];
        #pragma unroll
        for (int d = 32; d > 0; d >>= 1) p += __shfl_xor(p, d, 64);
        e[k] = p + b2[k];
    }
    float mx = e[0];
    #pragma unroll
    for (int k = 1; k < 9; ++k) mx = fmaxf(mx, e[k]);
    float ssum = 0.f;
    #pragma unroll
    for (int k = 0; k < 9; ++k){ e[k] = __expf(e[k]-mx); ssum += e[k]; }
    float inv = (1.0f/9.0f) / ssum;   // fold mean's 1/9 into attn

    // zero-padded attention table: Ap[i+1][j+1] = attn[i*3+j]
    float Ap[5][5];
    #pragma unroll
    for (int i = 0; i < 5; ++i)
        #pragma unroll
        for (int j = 0; j < 5; ++j) Ap[i][j] = 0.f;
    #pragma unroll
    for (int i = 0; i < 3; ++i)
        #pragma unroll
        for (int j = 0; j < 3; ++j) Ap[i+1][j+1] = e[i*3+j]*inv;

    bool dy1 = (y1i > y0i), dx1 = (x1i > x0i);
    float acc = 0.f;
    #pragma unroll
    for (int a = 0; a < 4; ++a){
        int ry = y0i - 1 + a;
        bool rok = (ry >= 0) && (ry < H_);
        #pragma unroll
        for (int bb = 0; bb < 4; ++bb){
            int rx = x0i - 1 + bb;
            float t00 = Ap[a+1][bb+1];
            float t01 = dx1 ? Ap[a+1][bb] : Ap[a+1][bb+1];
            float t10 = dy1 ? Ap[a][bb+1] : Ap[a+1][bb+1];
            float t11 = dy1 ? (dx1 ? Ap[a][bb] : Ap[a][bb+1])
                            : (dx1 ? Ap[a+1][bb] : Ap[a+1][bb+1]);
            float cw = wy0*wx0*t00 + wy0*wx*t01 + wy*wx0*t10 + wy*wx*t11;
            if (rok && rx >= 0 && rx < W_){
                float val = tierA ? bf2f(nbhT[pb + (size_t)(ry*W_+rx)*64 + lane])
                                  : nbhRaw[((long)(b*64 + lane))*HW_ + ry*W_ + rx];
                acc += cw * val;
            }
        }
    }
    if (tierA) outT[pb + (size_t)(y*W_+x)*64 + lane] = f2bf(acc);
    else       outN[((long)(b*64 + lane))*HW_ + y*W_ + x] = acc;
}

// ---------------------------------------------------------------------------
// K5 (tier A only): bf16 NHWC -> FP32 NCHW output
__global__ void k_t_bwd(const u16* __restrict__ outT, float* __restrict__ out){
    __shared__ u16 tile[64*66];
    int px0 = blockIdx.x * 64;
    int b   = blockIdx.y;
    int t   = threadIdx.x;
    #pragma unroll
    for (int it = 0; it < 16; ++it){
        int c  = t & 63;                     // coalesced along c
        int px = it*4 + (t>>6);
        tile[c*66+px] = outT[(size_t)(b*HW_ + px0 + px)*64 + c];
    }
    __syncthreads();
    #pragma unroll
    for (int it = 0; it < 16; ++it){
        int c  = it*4 + (t>>6);
        int px = t & 63;                     // coalesced fp32 stores along px
        out[(long)(b*64 + c)*HW_ + px0 + px] = bf2f(tile[c*66+px]);
    }
}

// ---------------------------------------------------------------------------
extern "C" void kernel_launch(void* const* d_in, const int* in_sizes, int n_in,
                              void* d_out, int out_size, void* d_ws, size_t ws_size,
                              hipStream_t stream){
    const float* nbh = (const float*)d_in[0];
    const float* cen = (const float*)d_in[1];
    const float* mv  = (const float*)d_in[2];
    const float* w1  = (const float*)d_in[3];
    const float* b1  = (const float*)d_in[4];
    const float* w2  = (const float*)d_in[5];
    const float* b2  = (const float*)d_in[6];
    float* out = (float*)d_out;              // reference output dtype = float32

    const size_t IMG = (size_t)B_*HW_*64;    // 4,194,304 elements
    char* ws = (char*)d_ws;
    u16* WtA   = (u16*)ws;                   // 36864 u16
    u16* WtB   = WtA + 64*576;
    u16* convA = (u16*)(ws + 147456);        // bf16 NHWC conv fields
    u16* convB = convA + IMG;
    u16* nbhT  = convB + IMG;                // tier A only
    u16* outT  = nbhT  + IMG;                // tier A only

    const size_t needA = 147456ull + 4ull*IMG*2ull;   // ~33.7 MB
    int tierA = (ws_size >= needA) ? 1 : 0;

    hipLaunchKernelGGL(k_prep_w, dim3(64,2), dim3(576), 0, stream, w1, WtA, WtB);
    if (tierA)
        hipLaunchKernelGGL(k_t_nbh, dim3(256,4), dim3(256), 0, stream, nbh, nbhT);
    hipLaunchKernelGGL(k_conv, dim3(2,128,8), dim3(256), 0, stream,
                       nbh, cen, WtA, WtB, convA, convB);
    hipLaunchKernelGGL(k_attn, dim3(16384), dim3(256), 0, stream,
                       nbh, nbhT, convA, convB, mv, b1, w2, b2,
                       outT, out, tierA);
    if (tierA)
        hipLaunchKernelGGL(k_t_bwd, dim3(256,4), dim3(256), 0, stream, outT, out);
}

// Round 6
// 186.827 us; speedup vs baseline: 1.1586x; 1.1586x over previous
//
#include <hip/hip_runtime.h>

#define B_   4
#define H_   128
#define W_   128
#define HW_  (H_*W_)     // 16384
#define CIN_ 1152
#define CP   72          // padded channel stride in LDS (144 B, 16B-aligned)

typedef __attribute__((ext_vector_type(8))) short short8;
typedef __attribute__((ext_vector_type(4))) float floatx4;
typedef unsigned short u16;
typedef unsigned int   u32;

__device__ __forceinline__ float bf2f(u16 u){ union{u32 i; float f;} v; v.i=((u32)u)<<16; return v.f; }
__device__ __forceinline__ u16 f2bf(float f){ union{float fl; u32 i;} v; v.fl=f; u32 lsb=(v.i>>16)&1u; v.i += 0x7fffu + lsb; return (u16)(v.i>>16); }

// ---------------------------------------------------------------------------
// K1: re-layout w1 (fp32 [64][1152], col = half*576 + c*9 + ij) into bf16
//     Wt{A,B}[o][ij*64 + c]
__global__ void k_prep_w(const float* __restrict__ w1,
                         u16* __restrict__ WtA, u16* __restrict__ WtB){
    int o = blockIdx.x, sel = blockIdx.y, k = threadIdx.x;   // k in [0,576)
    int c = k & 63, ij = k >> 6;
    float v = w1[(long)o*CIN_ + sel*576 + c*9 + ij];
    u16* dst = sel ? WtB : WtA;
    dst[o*576 + ij*64 + c] = f2bf(v);
}

// ---------------------------------------------------------------------------
// K2: fp32 NCHW -> bf16 NHWC, vectorized (float4 reads, uint2 writes).
//     z=0: nbh->nbhT, z=1: cen->cenT. 64px x 64c tile per block.
__global__ __launch_bounds__(256) void k_t_fwd(
        const float* __restrict__ nbh, const float* __restrict__ cen,
        u16* __restrict__ nbhT, u16* __restrict__ cenT){
    __shared__ u16 tile[64*68];
    int px0 = blockIdx.x * 64;
    int b   = blockIdx.y;
    const float* src = blockIdx.z ? cen : nbh;
    u16* dst         = blockIdx.z ? cenT : nbhT;
    int t  = threadIdx.x;
    int hi = t >> 4, seg = t & 15;
    #pragma unroll
    for (int p = 0; p < 4; ++p){
        int c = p*16 + hi;
        float4 v = *reinterpret_cast<const float4*>(&src[(size_t)(b*64 + c)*HW_ + px0 + seg*4]);
        u16 pk[4] = { f2bf(v.x), f2bf(v.y), f2bf(v.z), f2bf(v.w) };
        *reinterpret_cast<uint2*>(&tile[c*68 + seg*4]) = *reinterpret_cast<uint2*>(pk);
    }
    __syncthreads();
    #pragma unroll
    for (int p = 0; p < 4; ++p){
        int px = p*16 + hi;
        int cg = seg*4;
        u16 pk[4] = { tile[cg*68+px], tile[(cg+1)*68+px], tile[(cg+2)*68+px], tile[(cg+3)*68+px] };
        *reinterpret_cast<uint2*>(&dst[(size_t)(b*HW_ + px0 + px)*64 + cg]) = *reinterpret_cast<uint2*>(pk);
    }
}

// ---------------------------------------------------------------------------
// K3 v3: 3x3 conv cin=64 -> cout=64, zero pad, MFMA 16x16x32 bf16.
//     Block: 2 rows x 64 cols x 64 outs; 4 waves, each 32px x 64out.
//     Stages from bf16 NHWC with uint4 loads (was: scalar fp32 + div).
__global__ __launch_bounds__(256) void k_conv(
        const u16* __restrict__ nbhT, const u16* __restrict__ cenT,
        const u16* __restrict__ WtA, const u16* __restrict__ WtB,
        u16* __restrict__ convA, u16* __restrict__ convB){
    __shared__ __align__(16) u16 patch[4*66*CP];   // rows y0-1..y0+2, cols x0-1..x0+64
    __shared__ __align__(16) u16 wtile[64*CP];     // [o][c] for current shift
    int x0  = blockIdx.x * 64;
    int y0  = blockIdx.y * 2;
    int b   = blockIdx.z >> 1;
    int sel = blockIdx.z & 1;
    const u16* src = sel ? cenT : nbhT;
    const u16* wt  = sel ? WtB : WtA;
    u16* dst       = sel ? convB : convA;
    int tid = threadIdx.x;

    // stage 4 input rows (zero OOB = unfold's zero padding), 16 B vector loads
    #pragma unroll
    for (int r = 0; r < 4; ++r){
        int gy = y0 - 1 + r;
        bool rok = (gy >= 0) && (gy < H_);
        for (int q = tid; q < 66*8; q += 256){
            int col = q >> 3, c8 = q & 7;
            int gx = x0 - 1 + col;
            uint4 val = make_uint4(0u,0u,0u,0u);
            if (rok && gx >= 0 && gx < W_)
                val = *reinterpret_cast<const uint4*>(&src[((size_t)(b*HW_ + gy*W_ + gx))*64 + c8*8]);
            *reinterpret_cast<uint4*>(&patch[(r*66 + col)*CP + c8*8]) = val;
        }
    }

    int lane = tid & 63;
    int m    = lane & 15;
    int qd   = lane >> 4;
    int w    = tid >> 6;          // wave id
    int row  = w & 1;             // local row
    int xoff = (w >> 1) * 32;     // x-half

    floatx4 acc[2][4] = {};

    #pragma unroll
    for (int ij = 0; ij < 9; ++ij){
        const int i = ij / 3, j = ij % 3;
        __syncthreads();                       // covers patch staging at ij==0
        for (int q = tid; q < 64*8; q += 256){ // stage 64x64 weight tile
            int o = q >> 3, c8 = q & 7;
            *reinterpret_cast<uint4*>(&wtile[o*CP + c8*8]) =
                *reinterpret_cast<const uint4*>(&wt[o*576 + ij*64 + c8*8]);
        }
        __syncthreads();
        #pragma unroll
        for (int s = 0; s < 2; ++s){
            int c0 = s*32 + qd*8;
            short8 bv[4];
            #pragma unroll
            for (int nt = 0; nt < 4; ++nt)
                bv[nt] = *reinterpret_cast<const short8*>(&wtile[(nt*16 + m)*CP + c0]);
            #pragma unroll
            for (int mt = 0; mt < 2; ++mt){
                short8 av = *reinterpret_cast<const short8*>(
                    &patch[((row + i)*66 + xoff + mt*16 + m + j)*CP + c0]);
                #pragma unroll
                for (int nt = 0; nt < 4; ++nt)
                    acc[mt][nt] = __builtin_amdgcn_mfma_f32_16x16x32_bf16(av, bv[nt], acc[mt][nt], 0, 0, 0);
            }
        }
    }

    // C/D layout: col(o-local) = lane&15, row(px-local) = quad*4 + reg
    size_t base = ((size_t)(b*HW_ + (y0 + row)*W_ + x0))*64;
    #pragma unroll
    for (int mt = 0; mt < 2; ++mt)
        #pragma unroll
        for (int nt = 0; nt < 4; ++nt)
            #pragma unroll
            for (int r = 0; r < 4; ++r){
                int px = xoff + mt*16 + qd*4 + r;
                int o  = nt*16 + m;
                dst[base + (size_t)px*64 + o] = f2bf(acc[mt][nt][r]);
            }
}

// ---------------------------------------------------------------------------
// att-table fetch for tap lanes: att value at padded-table coords (i,j),
// distributed one per lane (lane k of each 16-group holds att[k]).
__device__ __forceinline__ float fetchA(float am, int lane, int i, int j){
    bool ok = (i >= 1) & (i <= 3) & (j >= 1) & (j <= 3);
    int k = (i-1)*3 + (j-1);
    k = min(max(k, 0), 8);
    float v = __shfl(am, (lane & 48) | k, 64);
    return ok ? v : 0.f;
}

// K4 v2: one wave per pixel. Butterfly h2 reductions kept; the 16 combined
// tap weights are now computed ONE-PER-LANE (t = lane&15) via shfl from
// lane-distributed att values, then broadcast back in the tap loop.
__global__ __launch_bounds__(256) void k_attn(
        const u16* __restrict__ nbhT,
        const u16* __restrict__ convA, const u16* __restrict__ convB,
        const float* __restrict__ mv,
        const float* __restrict__ b1, const float* __restrict__ w2,
        const float* __restrict__ b2, u16* __restrict__ outT){
    int tid  = threadIdx.x;
    int lane = tid & 63;
    int P    = blockIdx.x*4 + (tid >> 6);
    int b    = P >> 14;
    int rem  = P & 16383;
    int y    = rem >> 7;
    int x    = rem & 127;

    // u = mv0/W*2*32 = 0.5*mv0 ; align_corners=True
    float u  = mv[(long)(b*2  )*HW_ + y*W_ + x] * 0.5f;
    float v  = mv[(long)(b*2+1)*HW_ + y*W_ + x] * 0.5f;
    float gx = fminf(fmaxf(-1.0f + x*(2.0f/127.0f) + u, -1.f), 1.f);
    float gy = fminf(fmaxf(-1.0f + y*(2.0f/127.0f) + v, -1.f), 1.f);
    float sx = (gx + 1.f) * 63.5f;
    float sy = (gy + 1.f) * 63.5f;
    float x0f = floorf(sx), y0f = floorf(sy);
    float wx = sx - x0f,    wy = sy - y0f;
    int x0i = min(max((int)x0f, 0), W_-1);
    int y0i = min(max((int)y0f, 0), H_-1);
    int x1i = min(x0i+1, W_-1);
    int y1i = min(y0i+1, H_-1);
    float wx0 = 1.f - wx, wy0 = 1.f - wy;

    size_t pb = (size_t)b*HW_*64;
    int o = lane;
    float v00 = bf2f(convA[pb + (size_t)(y0i*W_+x0i)*64 + o]);
    float v01 = bf2f(convA[pb + (size_t)(y0i*W_+x1i)*64 + o]);
    float v10 = bf2f(convA[pb + (size_t)(y1i*W_+x0i)*64 + o]);
    float v11 = bf2f(convA[pb + (size_t)(y1i*W_+x1i)*64 + o]);
    float h1 = wy0*wx0*v00 + wy0*wx*v01 + wy*wx0*v10 + wy*wx*v11
             + bf2f(convB[pb + (size_t)(y*W_+x)*64 + o]) + b1[o];
    h1 = h1 >= 0.f ? h1 : 0.1f*h1;   // LeakyReLU(0.1)

    float e[9];
    #pragma unroll
    for (int k = 0; k < 9; ++k){
        float p = h1 * w2[k*64 + o];
        #pragma unroll
        for (int d = 32; d > 0; d >>= 1) p += __shfl_xor(p, d, 64);
        e[k] = p + b2[k];
    }
    float mx = e[0];
    #pragma unroll
    for (int k = 1; k < 9; ++k) mx = fmaxf(mx, e[k]);
    float ssum = 0.f;
    #pragma unroll
    for (int k = 0; k < 9; ++k){ e[k] = __expf(e[k]-mx); ssum += e[k]; }
    float inv = (1.0f/9.0f) / ssum;   // fold mean's 1/9 into attn

    // distribute att over lanes: lane k of each 16-group holds att[k]
    int kk = lane & 15;
    float am = 0.f;
    #pragma unroll
    for (int k = 0; k < 9; ++k) am = (kk == k) ? e[k]*inv : am;

    // lane t = lane&15 computes combined weight for tap t = (a,bb)
    bool dy1 = (y1i > y0i), dx1 = (x1i > x0i);
    int tt = lane & 15, a = tt >> 2, bb = tt & 3;
    int i0 = a+1,            j0 = bb+1;
    int i1 = a+1,            j1 = dx1 ? bb : bb+1;
    int i2 = dy1 ? a : a+1,  j2 = bb+1;
    int i3 = i2,             j3 = j1;
    float cw = wy0*wx0*fetchA(am,lane,i0,j0) + wy0*wx *fetchA(am,lane,i1,j1)
             + wy *wx0*fetchA(am,lane,i2,j2) + wy *wx *fetchA(am,lane,i3,j3);

    float acc = 0.f;
    #pragma unroll
    for (int t = 0; t < 16; ++t){
        int ry = y0i - 1 + (t >> 2);      // wave-uniform -> scalar branch
        int rx = x0i - 1 + (t & 3);
        if (ry >= 0 && ry < H_ && rx >= 0 && rx < W_){
            float cwt = __shfl(cw, (lane & 48) | t, 64);
            acc += cwt * bf2f(nbhT[pb + (size_t)(ry*W_+rx)*64 + lane]);
        }
    }
    outT[pb + (size_t)(y*W_+x)*64 + lane] = f2bf(acc);
}

// ---------------------------------------------------------------------------
// K5: bf16 NHWC -> fp32 NCHW output, vectorized (uint2 reads, float4 writes)
__global__ __launch_bounds__(256) void k_t_bwd(const u16* __restrict__ outT,
                                               float* __restrict__ out){
    __shared__ u16 tile[64*68];
    int px0 = blockIdx.x * 64;
    int b   = blockIdx.y;
    int t   = threadIdx.x;
    int hi  = t >> 4, seg = t & 15;
    #pragma unroll
    for (int p = 0; p < 4; ++p){
        int px = p*16 + hi;
        int cg = seg*4;
        uint2 r = *reinterpret_cast<const uint2*>(&outT[(size_t)(b*HW_ + px0 + px)*64 + cg]);
        const u16* pk = reinterpret_cast<const u16*>(&r);
        tile[(cg+0)*68+px] = pk[0]; tile[(cg+1)*68+px] = pk[1];
        tile[(cg+2)*68+px] = pk[2]; tile[(cg+3)*68+px] = pk[3];
    }
    __syncthreads();
    #pragma unroll
    for (int p = 0; p < 4; ++p){
        int c = p*16 + hi;
        float4 v;
        v.x = bf2f(tile[c*68 + seg*4 + 0]);
        v.y = bf2f(tile[c*68 + seg*4 + 1]);
        v.z = bf2f(tile[c*68 + seg*4 + 2]);
        v.w = bf2f(tile[c*68 + seg*4 + 3]);
        *reinterpret_cast<float4*>(&out[(size_t)(b*64 + c)*HW_ + px0 + seg*4]) = v;
    }
}

// ---------------------------------------------------------------------------
extern "C" void kernel_launch(void* const* d_in, const int* in_sizes, int n_in,
                              void* d_out, int out_size, void* d_ws, size_t ws_size,
                              hipStream_t stream){
    const float* nbh = (const float*)d_in[0];
    const float* cen = (const float*)d_in[1];
    const float* mv  = (const float*)d_in[2];
    const float* w1  = (const float*)d_in[3];
    const float* b1  = (const float*)d_in[4];
    const float* w2  = (const float*)d_in[5];
    const float* b2  = (const float*)d_in[6];
    float* out = (float*)d_out;

    const size_t IMG = (size_t)B_*HW_*64;    // 4,194,304 elements
    char* ws = (char*)d_ws;
    u16* WtA   = (u16*)ws;                   // 73728 B
    u16* WtB   = WtA + 64*576;               // ends 147456
    u16* convA = (u16*)(ws + 147456);
    u16* convB = convA + IMG;
    u16* nbhT  = convB + IMG;
    u16* cenT  = nbhT  + IMG;                // ALIASED: cenT dead after k_conv,
    u16* outT  = cenT;                       // reused as outT by k_attn.
    // total footprint: 147456 + 4*IMG*2 = 33,701,888 B (proven safe: r2/r3
    // bit-identical outputs established ws >= ~42 MB)

    hipLaunchKernelGGL(k_prep_w, dim3(64,2),    dim3(576), 0, stream, w1, WtA, WtB);
    hipLaunchKernelGGL(k_t_fwd,  dim3(256,4,2), dim3(256), 0, stream, nbh, cen, nbhT, cenT);
    hipLaunchKernelGGL(k_conv,   dim3(2,64,8),  dim3(256), 0, stream,
                       nbhT, cenT, WtA, WtB, convA, convB);
    hipLaunchKernelGGL(k_attn,   dim3(16384),   dim3(256), 0, stream,
                       nbhT, convA, convB, mv, b1, w2, b2, outT);
    hipLaunchKernelGGL(k_t_bwd,  dim3(256,4),   dim3(256), 0, stream, outT, out);
}

// Round 7
// 152.235 us; speedup vs baseline: 1.4219x; 1.2272x over previous
//
#include <hip/hip_runtime.h>

#define B_   4
#define H_   128
#define W_   128
#define HW_  (H_*W_)     // 16384
#define CIN_ 1152
#define CP   72          // padded px stride in LDS patch (144 B)

typedef __attribute__((ext_vector_type(8))) short short8;
typedef __attribute__((ext_vector_type(4))) float floatx4;
typedef unsigned short u16;
typedef unsigned int   u32;

__device__ __forceinline__ float bf2f(u16 u){ union{u32 i; float f;} v; v.i=((u32)u)<<16; return v.f; }
__device__ __forceinline__ u16 f2bf(float f){ union{float fl; u32 i;} v; v.fl=f; u32 lsb=(v.i>>16)&1u; v.i += 0x7fffu + lsb; return (u16)(v.i>>16); }

// ---------------------------------------------------------------------------
// K1: re-layout w1 (fp32 [64][1152], col = half*576 + c*9 + ij) into bf16
//     Wt{A,B}[o][ij*64 + c]
__global__ void k_prep_w(const float* __restrict__ w1,
                         u16* __restrict__ WtA, u16* __restrict__ WtB){
    int o = blockIdx.x, sel = blockIdx.y, k = threadIdx.x;   // k in [0,576)
    int c = k & 63, ij = k >> 6;
    float v = w1[(long)o*CIN_ + sel*576 + c*9 + ij];
    u16* dst = sel ? WtB : WtA;
    dst[o*576 + ij*64 + c] = f2bf(v);
}

// ---------------------------------------------------------------------------
// K2: fp32 NCHW -> bf16 NHWC, vectorized (float4 reads, uint2 writes).
__global__ __launch_bounds__(256) void k_t_fwd(
        const float* __restrict__ nbh, const float* __restrict__ cen,
        u16* __restrict__ nbhT, u16* __restrict__ cenT){
    __shared__ u16 tile[64*68];
    int px0 = blockIdx.x * 64;
    int b   = blockIdx.y;
    const float* src = blockIdx.z ? cen : nbh;
    u16* dst         = blockIdx.z ? cenT : nbhT;
    int t  = threadIdx.x;
    int hi = t >> 4, seg = t & 15;
    #pragma unroll
    for (int p = 0; p < 4; ++p){
        int c = p*16 + hi;
        float4 v = *reinterpret_cast<const float4*>(&src[(size_t)(b*64 + c)*HW_ + px0 + seg*4]);
        u16 pk[4] = { f2bf(v.x), f2bf(v.y), f2bf(v.z), f2bf(v.w) };
        *reinterpret_cast<uint2*>(&tile[c*68 + seg*4]) = *reinterpret_cast<uint2*>(pk);
    }
    __syncthreads();
    #pragma unroll
    for (int p = 0; p < 4; ++p){
        int px = p*16 + hi;
        int cg = seg*4;
        u16 pk[4] = { tile[cg*68+px], tile[(cg+1)*68+px], tile[(cg+2)*68+px], tile[(cg+3)*68+px] };
        *reinterpret_cast<uint2*>(&dst[(size_t)(b*HW_ + px0 + px)*64 + cg]) = *reinterpret_cast<uint2*>(pk);
    }
}

// ---------------------------------------------------------------------------
// K3 v4: 3x3 conv cin=64->cout=64, zero pad, MFMA 16x16x32 bf16.
//     Block: 4 rows x 64 cols; ALL 9 weight tiles staged once (stride 64,
//     conflict-free: bv reads broadcast within qd); ONE barrier (was 18).
//     Wave w = row w, 4 x-quarters (mt) x 4 out-tiles (nt).
__global__ __launch_bounds__(256) void k_conv(
        const u16* __restrict__ nbhT, const u16* __restrict__ cenT,
        const u16* __restrict__ WtA, const u16* __restrict__ WtB,
        u16* __restrict__ convA, u16* __restrict__ convB){
    __shared__ __align__(16) u16 patch[6*66*CP];   // 57,024 B
    __shared__ __align__(16) u16 wall[9*64*64];    // 73,728 B
    int x0  = blockIdx.x * 64;
    int y0  = blockIdx.y * 4;
    int b   = blockIdx.z >> 1;
    int sel = blockIdx.z & 1;
    const u16* src = sel ? cenT : nbhT;
    const u16* wt  = sel ? WtB : WtA;
    u16* dst       = sel ? convB : convA;
    int tid = threadIdx.x;

    // stage all 9 weight tiles: wall[(ij*64+o)*64 + c]
    for (int q = tid; q < 9*64*8; q += 256){
        int row = q >> 3, c8 = q & 7;              // row = ij*64 + o
        int o = row & 63, ij = row >> 6;
        *reinterpret_cast<uint4*>(&wall[row*64 + c8*8]) =
            *reinterpret_cast<const uint4*>(&wt[o*576 + ij*64 + c8*8]);
    }
    // stage 6 input rows (zero OOB = unfold's zero padding)
    #pragma unroll
    for (int r = 0; r < 6; ++r){
        int gy = y0 - 1 + r;
        bool rok = (gy >= 0) && (gy < H_);
        for (int q = tid; q < 66*8; q += 256){
            int col = q >> 3, c8 = q & 7;
            int gx = x0 - 1 + col;
            uint4 val = make_uint4(0u,0u,0u,0u);
            if (rok && gx >= 0 && gx < W_)
                val = *reinterpret_cast<const uint4*>(&src[((size_t)(b*HW_ + gy*W_ + gx))*64 + c8*8]);
            *reinterpret_cast<uint4*>(&patch[(r*66 + col)*CP + c8*8]) = val;
        }
    }
    __syncthreads();

    int lane = tid & 63;
    int m    = lane & 15;
    int qd   = lane >> 4;
    int w    = tid >> 6;          // wave = local row

    floatx4 acc[4][4] = {};
    #pragma unroll
    for (int ij = 0; ij < 9; ++ij){
        const int i = ij/3, j = ij%3;
        #pragma unroll
        for (int s = 0; s < 2; ++s){
            int c0 = s*32 + qd*8;
            short8 bv[4];
            #pragma unroll
            for (int nt = 0; nt < 4; ++nt)
                bv[nt] = *reinterpret_cast<const short8*>(&wall[(ij*64 + nt*16 + m)*64 + c0]);
            #pragma unroll
            for (int mt = 0; mt < 4; ++mt){
                short8 av = *reinterpret_cast<const short8*>(
                    &patch[((w + i)*66 + mt*16 + m + j)*CP + c0]);
                #pragma unroll
                for (int nt = 0; nt < 4; ++nt)
                    acc[mt][nt] = __builtin_amdgcn_mfma_f32_16x16x32_bf16(av, bv[nt], acc[mt][nt], 0, 0, 0);
            }
        }
    }

    // C/D layout: col(o-local) = lane&15, row(px-local) = quad*4 + reg
    size_t base = ((size_t)(b*HW_ + (y0 + w)*W_ + x0))*64;
    #pragma unroll
    for (int mt = 0; mt < 4; ++mt)
        #pragma unroll
        for (int nt = 0; nt < 4; ++nt)
            #pragma unroll
            for (int r = 0; r < 4; ++r){
                int px = mt*16 + qd*4 + r;
                int o  = nt*16 + m;
                dst[base + (size_t)px*64 + o] = f2bf(acc[mt][nt][r]);
            }
}

// ---------------------------------------------------------------------------
// att fetch: attn value k=(i-1)*3+(j-1) from lane-distributed am within the
// 16-lane group; 0 if (i,j) outside the 3x3 table (padded coords 1..3).
__device__ __forceinline__ float fetchA(float am, int lane, int i, int j){
    bool ok = (i >= 1) & (i <= 3) & (j >= 1) & (j <= 3);
    int k = (i-1)*3 + (j-1);
    k = min(max(k, 0), 8);
    float v = __shfl(am, (lane & 48) | k, 64);
    return ok ? v : 0.f;
}

// K4 v3: 16 pixels per wave. Phase 1: lane m=pixel builds h1 A-frags (bilinear
// of convA + convB + b1, leaky), 2 MFMAs vs w2 B-frags -> logits; 16-wide shfl
// softmax; lane t computes cw[t] per pixel; (cw,off) -> per-wave LDS table.
// Phase 2: lane=channel, 16-tap gather. No barriers (wave-self-contained).
__global__ __launch_bounds__(256) void k_attn(
        const u16* __restrict__ nbhT,
        const u16* __restrict__ convA, const u16* __restrict__ convB,
        const float* __restrict__ mv,
        const float* __restrict__ b1, const float* __restrict__ w2,
        const float* __restrict__ b2, u16* __restrict__ outT){
    __shared__ __align__(16) int cwoff[64*16*2];   // [slot][t] -> (cw_bits, off)
    int tid  = threadIdx.x;
    int lane = tid & 63;
    int w    = tid >> 6;
    int m    = lane & 15;
    int qd   = lane >> 4;
    int pix  = blockIdx.x*64 + w*16 + m;
    int b    = pix >> 14;
    int y    = (pix >> 7) & 127;
    int x    = pix & 127;
    size_t pb = (size_t)b*HW_*64;

    // geometry (per pixel m, duplicated across qd)
    float u  = mv[(long)(b*2  )*HW_ + y*W_ + x] * 0.5f;
    float v  = mv[(long)(b*2+1)*HW_ + y*W_ + x] * 0.5f;
    float gx = fminf(fmaxf(-1.0f + x*(2.0f/127.0f) + u, -1.f), 1.f);
    float gy = fminf(fmaxf(-1.0f + y*(2.0f/127.0f) + v, -1.f), 1.f);
    float sx = (gx + 1.f) * 63.5f;
    float sy = (gy + 1.f) * 63.5f;
    float x0f = floorf(sx), y0f = floorf(sy);
    float wx = sx - x0f,    wy = sy - y0f;
    int x0i = min(max((int)x0f, 0), W_-1);
    int y0i = min(max((int)y0f, 0), H_-1);
    int x1i = min(x0i+1, W_-1);
    int y1i = min(y0i+1, H_-1);
    float wx0 = 1.f - wx, wy0 = 1.f - wy;

    // h1 A-fragments: channels c0 = s*32 + qd*8 (+j), pixel = m
    short8 av[2];
    #pragma unroll
    for (int s = 0; s < 2; ++s){
        int c0 = s*32 + qd*8;
        short8 q00 = *reinterpret_cast<const short8*>(&convA[pb + (size_t)(y0i*W_+x0i)*64 + c0]);
        short8 q01 = *reinterpret_cast<const short8*>(&convA[pb + (size_t)(y0i*W_+x1i)*64 + c0]);
        short8 q10 = *reinterpret_cast<const short8*>(&convA[pb + (size_t)(y1i*W_+x0i)*64 + c0]);
        short8 q11 = *reinterpret_cast<const short8*>(&convA[pb + (size_t)(y1i*W_+x1i)*64 + c0]);
        short8 qc  = *reinterpret_cast<const short8*>(&convB[pb + (size_t)(y*W_+x)*64 + c0]);
        short8 h;
        #pragma unroll
        for (int j = 0; j < 8; ++j){
            float t = wy0*(wx0*bf2f((u16)q00[j]) + wx*bf2f((u16)q01[j]))
                    + wy *(wx0*bf2f((u16)q10[j]) + wx*bf2f((u16)q11[j]))
                    + bf2f((u16)qc[j]) + b1[c0+j];
            t = t >= 0.f ? t : 0.1f*t;           // LeakyReLU(0.1)
            h[j] = (short)f2bf(t);
        }
        av[s] = h;
    }
    // w2 B-fragments: out-col kk = m, channels c0 = s*32 + qd*8
    short8 bv[2];
    #pragma unroll
    for (int s = 0; s < 2; ++s){
        int c0 = s*32 + qd*8;
        short8 t = {0,0,0,0,0,0,0,0};
        if (m < 9){
            #pragma unroll
            for (int j = 0; j < 8; ++j) t[j] = (short)f2bf(w2[m*64 + c0 + j]);
        }
        bv[s] = t;
    }
    floatx4 C = {0.f,0.f,0.f,0.f};
    C = __builtin_amdgcn_mfma_f32_16x16x32_bf16(av[0], bv[0], C, 0, 0, 0);
    C = __builtin_amdgcn_mfma_f32_16x16x32_bf16(av[1], bv[1], C, 0, 0, 0);
    // C layout: col = kk = lane&15, row = pixel-local = qd*4 + r

    float b2k = (m < 9) ? b2[m] : 0.f;
    float am[4];
    #pragma unroll
    for (int r = 0; r < 4; ++r){
        float e  = C[r] + b2k;
        float mx = (m < 9) ? e : -3.0e38f;
        #pragma unroll
        for (int d = 1; d < 16; d <<= 1) mx = fmaxf(mx, __shfl_xor(mx, d, 64));
        float a = (m < 9) ? __expf(e - mx) : 0.f;
        float s = a;
        #pragma unroll
        for (int d = 1; d < 16; d <<= 1) s += __shfl_xor(s, d, 64);
        am[r] = a / (9.f * s);                   // attn/9 (mean folded in)
    }

    // cw + offset per (pixel p = qd*4+r, tap t = m)
    int gpack = x0i | (y0i << 8) | ((y1i > y0i) ? 0x10000 : 0) | ((x1i > x0i) ? 0x20000 : 0);
    int at = m >> 2, bt = m & 3;
    #pragma unroll
    for (int r = 0; r < 4; ++r){
        int p   = qd*4 + r;
        int src = (lane & 48) | p;
        float wxp = __shfl(wx, src, 64);
        float wyp = __shfl(wy, src, 64);
        int   gp  = __shfl(gpack, src, 64);
        int x0p = gp & 255, y0p = (gp >> 8) & 255;
        int dy1 = (gp >> 16) & 1, dx1 = (gp >> 17) & 1;
        float wx0p = 1.f - wxp, wy0p = 1.f - wyp;
        int ia = dy1 ? at : at+1;
        int jb = dx1 ? bt : bt+1;
        float cw = wy0p*wx0p*fetchA(am[r], lane, at+1, bt+1)
                 + wy0p*wxp *fetchA(am[r], lane, at+1, jb)
                 + wyp *wx0p*fetchA(am[r], lane, ia,   bt+1)
                 + wyp *wxp *fetchA(am[r], lane, ia,   jb);
        int ry = y0p - 1 + at, rx = x0p - 1 + bt;
        bool ok = (ry >= 0) & (ry < H_) & (rx >= 0) & (rx < W_);
        int2 pr;
        pr.x = __float_as_int(ok ? cw : 0.f);
        pr.y = ok ? (ry*W_ + rx)*64 : 0;
        *reinterpret_cast<int2*>(&cwoff[((w*16 + p)*16 + m)*2]) = pr;
    }

    // phase 2: wave's own 16 slots; lane = channel
    for (int s = 0; s < 16; ++s){
        int slot = w*16 + s;
        const int2* pr = reinterpret_cast<const int2*>(&cwoff[slot*16*2]);
        float acc = 0.f;
        #pragma unroll
        for (int t = 0; t < 16; ++t){
            int2 p = pr[t];                      // wave-uniform -> broadcast
            acc += __int_as_float(p.x) * bf2f(nbhT[pb + (size_t)p.y + lane]);
        }
        outT[(size_t)(blockIdx.x*64 + slot)*64 + lane] = f2bf(acc);
    }
}

// ---------------------------------------------------------------------------
// K5: bf16 NHWC -> fp32 NCHW output, vectorized
__global__ __launch_bounds__(256) void k_t_bwd(const u16* __restrict__ outT,
                                               float* __restrict__ out){
    __shared__ u16 tile[64*68];
    int px0 = blockIdx.x * 64;
    int b   = blockIdx.y;
    int t   = threadIdx.x;
    int hi  = t >> 4, seg = t & 15;
    #pragma unroll
    for (int p = 0; p < 4; ++p){
        int px = p*16 + hi;
        int cg = seg*4;
        uint2 r = *reinterpret_cast<const uint2*>(&outT[(size_t)(b*HW_ + px0 + px)*64 + cg]);
        const u16* pk = reinterpret_cast<const u16*>(&r);
        tile[(cg+0)*68+px] = pk[0]; tile[(cg+1)*68+px] = pk[1];
        tile[(cg+2)*68+px] = pk[2]; tile[(cg+3)*68+px] = pk[3];
    }
    __syncthreads();
    #pragma unroll
    for (int p = 0; p < 4; ++p){
        int c = p*16 + hi;
        float4 v;
        v.x = bf2f(tile[c*68 + seg*4 + 0]);
        v.y = bf2f(tile[c*68 + seg*4 + 1]);
        v.z = bf2f(tile[c*68 + seg*4 + 2]);
        v.w = bf2f(tile[c*68 + seg*4 + 3]);
        *reinterpret_cast<float4*>(&out[(size_t)(b*64 + c)*HW_ + px0 + seg*4]) = v;
    }
}

// ---------------------------------------------------------------------------
extern "C" void kernel_launch(void* const* d_in, const int* in_sizes, int n_in,
                              void* d_out, int out_size, void* d_ws, size_t ws_size,
                              hipStream_t stream){
    const float* nbh = (const float*)d_in[0];
    const float* cen = (const float*)d_in[1];
    const float* mv  = (const float*)d_in[2];
    const float* w1  = (const float*)d_in[3];
    const float* b1  = (const float*)d_in[4];
    const float* w2  = (const float*)d_in[5];
    const float* b2  = (const float*)d_in[6];
    float* out = (float*)d_out;

    const size_t IMG = (size_t)B_*HW_*64;    // 4,194,304 elements
    char* ws = (char*)d_ws;
    u16* WtA   = (u16*)ws;                   // 73728 B
    u16* WtB   = WtA + 64*576;               // ends 147456
    u16* convA = (u16*)(ws + 147456);
    u16* convB = convA + IMG;
    u16* nbhT  = convB + IMG;
    u16* cenT  = nbhT  + IMG;                // cenT dead after k_conv,
    u16* outT  = cenT;                       // reused as outT by k_attn.

    hipLaunchKernelGGL(k_prep_w, dim3(64,2),    dim3(576), 0, stream, w1, WtA, WtB);
    hipLaunchKernelGGL(k_t_fwd,  dim3(256,4,2), dim3(256), 0, stream, nbh, cen, nbhT, cenT);
    hipLaunchKernelGGL(k_conv,   dim3(2,32,8),  dim3(256), 0, stream,
                       nbhT, cenT, WtA, WtB, convA, convB);
    hipLaunchKernelGGL(k_attn,   dim3(1024),    dim3(256), 0, stream,
                       nbhT, convA, convB, mv, b1, w2, b2, outT);
    hipLaunchKernelGGL(k_t_bwd,  dim3(256,4),   dim3(256), 0, stream, outT, out);
}